// Round 4
// baseline (491.798 us; speedup 1.0000x reference)
//
#include <hip/hip_runtime.h>
#include <hip/hip_bf16.h>

typedef float f32x4 __attribute__((ext_vector_type(4)));
typedef __bf16 bf16x8 __attribute__((ext_vector_type(8)));
typedef unsigned short ushort_t;
typedef ushort_t u16x8 __attribute__((ext_vector_type(8)));

// ---------------------------------------------------------------------------
// fp32 -> bf16 round-to-nearest-even
// ---------------------------------------------------------------------------
__device__ inline ushort_t f2bf_rne(float f) {
  unsigned u = __builtin_bit_cast(unsigned, f);
  unsigned r = (u + 0x7fffu + ((u >> 16) & 1u)) >> 16;
  return (ushort_t)r;
}

// ---------------------------------------------------------------------------
// Kernel 1: 2:4 prune (exact fp32 argsort-stable semantics) + cast to bf16.
// ---------------------------------------------------------------------------
__global__ void prune_cast_kernel(const float* __restrict__ x,
                                  ushort_t* __restrict__ xsp, long n8) {
  long i = (long)blockIdx.x * blockDim.x + threadIdx.x;
  if (i >= n8) return;
  const float4* p = reinterpret_cast<const float4*>(x);
  float4 g0 = p[2 * i];
  float4 g1 = p[2 * i + 1];
  float v[8] = {g0.x, g0.y, g0.z, g0.w, g1.x, g1.y, g1.z, g1.w};
  u16x8 o;
#pragma unroll
  for (int g = 0; g < 2; ++g) {
    float a[4];
#pragma unroll
    for (int j = 0; j < 4; ++j) a[j] = fabsf(v[g * 4 + j]);
#pragma unroll
    for (int j = 0; j < 4; ++j) {
      int rank = 0;
#pragma unroll
      for (int k = 0; k < 4; ++k) {
        if (k == j) continue;
        rank += (a[k] < a[j]) || (a[k] == a[j] && k < j);
      }
      o[g * 4 + j] = (rank >= 2) ? f2bf_rne(v[g * 4 + j]) : (ushort_t)0;
    }
  }
  reinterpret_cast<u16x8*>(xsp)[i] = o;
}

// ---------------------------------------------------------------------------
// Kernel 2: fp32 -> bf16 cast of the weight matrix.
// ---------------------------------------------------------------------------
__global__ void cast_bf16_kernel(const float* __restrict__ w,
                                 ushort_t* __restrict__ wb, long n8) {
  long i = (long)blockIdx.x * blockDim.x + threadIdx.x;
  if (i >= n8) return;
  const float4* p = reinterpret_cast<const float4*>(w);
  float4 g0 = p[2 * i];
  float4 g1 = p[2 * i + 1];
  u16x8 o;
  o[0] = f2bf_rne(g0.x); o[1] = f2bf_rne(g0.y);
  o[2] = f2bf_rne(g0.z); o[3] = f2bf_rne(g0.w);
  o[4] = f2bf_rne(g1.x); o[5] = f2bf_rne(g1.y);
  o[6] = f2bf_rne(g1.z); o[7] = f2bf_rne(g1.w);
  reinterpret_cast<u16x8*>(wb)[i] = o;
}

// ---------------------------------------------------------------------------
// Kernel 3: 256x256 8-phase bf16 GEMM.  C[m][n] = sum_k A[m][k]*B[n][k].
// 8 waves (2Mx4N), BK=64, 128 KiB LDS double-buffered, 3-bit XOR swizzle
// (physical chunk = logical chunk ^ (row&7)), counted lgkm/vmcnt, raw
// barriers, setprio.
//
// Schedule (this round): tile t stages tile t+2 (A0@p1, B0B1@p2, A1@p3;
// each slot staged after its last same-parity read) -> every half-tile has
// ~2 tiles of flight; tile-end wait = vmcnt(8) (this tile's 8 loads).
// ds_read pipelining: b23 prefetched in ph0 (used ph1/ph2), afO (A-mh1)
// prefetched in ph1 (used ph2/ph3); counted lgkmcnt leaves prefetches in
// flight.
// ---------------------------------------------------------------------------
#define BAR() __builtin_amdgcn_s_barrier()
#define WAIT_LGKM0() asm volatile("s_waitcnt lgkmcnt(0)" ::: "memory")
#define WAIT_LGKM4() asm volatile("s_waitcnt lgkmcnt(4)" ::: "memory")
#define WAIT_LGKM8() asm volatile("s_waitcnt lgkmcnt(8)" ::: "memory")
#define WAIT_VM8() asm volatile("s_waitcnt vmcnt(8)" ::: "memory")
#define WAIT_VM0() asm volatile("s_waitcnt vmcnt(0)" ::: "memory")

#define STAGE_A(t1, h, par)                                                    \
  {                                                                            \
    const ushort_t* g0 =                                                       \
        A + (a_row0 + (h) * 128 + srow) * (long)Kd + (t1) * 64 + scol;         \
    const ushort_t* g1 =                                                       \
        A + (a_row0 + (h) * 128 + srow + 8) * (long)Kd + (t1) * 64 + scol;     \
    ushort_t* l0 = &ldsA[((par) * 2 + (h)) * 8192 + w * 1024];                 \
    __builtin_amdgcn_global_load_lds(                                          \
        (const __attribute__((address_space(1))) void*)g0,                     \
        (__attribute__((address_space(3))) void*)l0, 16, 0, 0);                \
    __builtin_amdgcn_global_load_lds(                                          \
        (const __attribute__((address_space(1))) void*)g1,                     \
        (__attribute__((address_space(3))) void*)(l0 + 512), 16, 0, 0);        \
  }

#define STAGE_B(t1, h, par)                                                    \
  {                                                                            \
    const ushort_t* g0 =                                                       \
        B + (b_row0 + (h) * 128 + srow) * (long)Kd + (t1) * 64 + scol;         \
    const ushort_t* g1 =                                                       \
        B + (b_row0 + (h) * 128 + srow + 8) * (long)Kd + (t1) * 64 + scol;     \
    ushort_t* l0 = &ldsB[((par) * 2 + (h)) * 8192 + w * 1024];                 \
    __builtin_amdgcn_global_load_lds(                                          \
        (const __attribute__((address_space(1))) void*)g0,                     \
        (__attribute__((address_space(3))) void*)l0, 16, 0, 0);                \
    __builtin_amdgcn_global_load_lds(                                          \
        (const __attribute__((address_space(1))) void*)g1,                     \
        (__attribute__((address_space(3))) void*)(l0 + 512), 16, 0, 0);        \
  }

#define LDA_FRAG(dst, par, mi, s)                                              \
  dst = *reinterpret_cast<const bf16x8*>(                                      \
      reinterpret_cast<const char*>(ldsA) + ((par) * 2 + wr) * 16384 +         \
      (mi) * 2048 + ((s) ? roff1 : roff0));

#define LDB_FRAG(dst, par, ni, s)                                              \
  dst = *reinterpret_cast<const bf16x8*>(                                      \
      reinterpret_cast<const char*>(ldsB) + ((par) * 2 + (wc >> 1)) * 16384 +  \
      (wc & 1) * 8192 + (ni) * 2048 + ((s) ? roff1 : roff0));

#define MFMA_Q(AF, BF, MH, NH)                                                 \
  __builtin_amdgcn_s_setprio(1);                                               \
  _Pragma("unroll") for (int s = 0; s < 2; ++s)                                \
  _Pragma("unroll") for (int mi = 0; mi < 4; ++mi)                             \
  _Pragma("unroll") for (int ni = 0; ni < 2; ++ni)                             \
      acc[(MH) * 4 + mi][(NH) * 2 + ni] =                                      \
          __builtin_amdgcn_mfma_f32_16x16x32_bf16(                             \
              AF[mi][s], BF[ni][s], acc[(MH) * 4 + mi][(NH) * 2 + ni],         \
              0, 0, 0);                                                        \
  __builtin_amdgcn_s_setprio(0);

#define KTILE(t, PAR)                                                          \
  { /* ph0: read afE(mh0)+b01 ; prefetch b23 ; MFMA Q(0,0) */                  \
    _Pragma("unroll") for (int mi = 0; mi < 4; ++mi)                           \
    _Pragma("unroll") for (int s = 0; s < 2; ++s)                              \
        LDA_FRAG(afE[mi][s], PAR, mi, s)                                       \
    _Pragma("unroll") for (int ni = 0; ni < 2; ++ni)                           \
    _Pragma("unroll") for (int s = 0; s < 2; ++s)                              \
        LDB_FRAG(b01[ni][s], PAR, ni, s)                                       \
    _Pragma("unroll") for (int ni = 0; ni < 2; ++ni)                           \
    _Pragma("unroll") for (int s = 0; s < 2; ++s)                              \
        LDB_FRAG(b23[ni][s], PAR, 2 + ni, s)                                   \
    BAR();                                                                     \
    WAIT_LGKM4();                                                              \
    MFMA_Q(afE, b01, 0, 0)                                                     \
    BAR();                                                                     \
    /* ph1: prefetch afO(mh1) ; stage A0(t+2) ; MFMA Q(0,1) */                 \
    _Pragma("unroll") for (int mi = 0; mi < 4; ++mi)                           \
    _Pragma("unroll") for (int s = 0; s < 2; ++s)                              \
        LDA_FRAG(afO[mi][s], PAR, 4 + mi, s)                                   \
    if ((t) + 2 < NT) STAGE_A((t) + 2, 0, PAR)                                 \
    BAR();                                                                     \
    WAIT_LGKM8();                                                              \
    MFMA_Q(afE, b23, 0, 1)                                                     \
    BAR();                                                                     \
    /* ph2: stage B0,B1(t+2) ; MFMA Q(1,1) */                                  \
    if ((t) + 2 < NT) { STAGE_B((t) + 2, 0, PAR) STAGE_B((t) + 2, 1, PAR) }    \
    BAR();                                                                     \
    WAIT_LGKM0();                                                              \
    MFMA_Q(afO, b23, 1, 1)                                                     \
    BAR();                                                                     \
    /* ph3: stage A1(t+2) ; MFMA Q(1,0) ; tile-end wait */                     \
    if ((t) + 2 < NT) STAGE_A((t) + 2, 1, PAR)                                 \
    BAR();                                                                     \
    MFMA_Q(afO, b01, 1, 0)                                                     \
    if ((t) + 2 < NT) { WAIT_VM8(); } else { WAIT_VM0(); }                     \
    BAR();                                                                     \
  }

__global__ __launch_bounds__(512, 1) void gemm256_kernel(
    const ushort_t* __restrict__ A,  // [M][K] bf16 (pruned x)
    const ushort_t* __restrict__ B,  // [N][K] bf16 (weight)
    float* __restrict__ C,           // [M][N] fp32
    int M, int N, int Kd) {
  __shared__ ushort_t ldsA[4 * 8192];  // 4 slots x 16 KiB (par,half)
  __shared__ ushort_t ldsB[4 * 8192];

  const int tid = threadIdx.x;
  const int lane = tid & 63;
  const int w = tid >> 6;   // wave 0..7
  const int wr = w >> 2;    // 0..1 -> 128-row half
  const int wc = w & 3;     // 0..3 -> 64-col slab

  // XCD-bijective grid swizzle (gridDim.x % 8 == 0)
  const int b = blockIdx.x;
  const int wg = (b & 7) * (gridDim.x >> 3) + (b >> 3);
  const int nbn = N / 256;
  const int bm = wg / nbn, bn = wg % nbn;
  const long a_row0 = (long)bm * 256;
  const long b_row0 = (long)bn * 256;
  const int NT = Kd / 64;

  // staging: instr i of wave w, lane l writes LINEAR physical (row
  // 16w+8i+(l>>3), chunk l&7); swizzle physical(r,c) <- logical(r, c^(r&7))
  // -> global SOURCE chunk = (l&7) ^ ((l>>3)&7)  (same for both instrs).
  const int srow = w * 16 + (lane >> 3);
  const int scol = (((lane & 7) ^ ((lane >> 3) & 7)) << 3);  // ushort units

  // fragment read: logical (row rl, chunk q|s<<2) -> physical chunk
  // (q|s<<2) ^ (rl&7); s is inside the XOR -> two precomputed offsets.
  const int rl = lane & 15;
  const int q = lane >> 4;
  const int roff0 = rl * 128 + (((q) ^ (rl & 7)) << 4);
  const int roff1 = rl * 128 + (((q | 4) ^ (rl & 7)) << 4);

  f32x4 acc[8][4];
#pragma unroll
  for (int i = 0; i < 8; ++i)
#pragma unroll
    for (int j = 0; j < 4; ++j) acc[i][j] = f32x4{0.f, 0.f, 0.f, 0.f};

  bf16x8 afE[4][2];  // A-mh0 fragments
  bf16x8 afO[4][2];  // A-mh1 fragments (prefetched ph1)
  bf16x8 b01[2][2];  // B n0..1 fragments
  bf16x8 b23[2][2];  // B n2..3 fragments (prefetched ph0)

  // ---- prologue: stage tiles 0 (par0) and 1 (par1) fully; wait tile0 ----
  STAGE_A(0, 0, 0)
  STAGE_A(0, 1, 0)
  STAGE_B(0, 0, 0)
  STAGE_B(0, 1, 0)
  STAGE_A(1, 0, 1)
  STAGE_A(1, 1, 1)
  STAGE_B(1, 0, 1)
  STAGE_B(1, 1, 1)
  WAIT_VM8();
  BAR();

  for (int t = 0; t < NT; t += 2) {
    KTILE(t, 0)
    KTILE(t + 1, 1)
  }

  // ---- epilogue: C/D layout col=lane&15, row=(lane>>4)*4+r ----
  const int orow = (lane >> 4) * 4;
  const int ocol = lane & 15;
#pragma unroll
  for (int mi = 0; mi < 8; ++mi)
#pragma unroll
    for (int ni = 0; ni < 4; ++ni) {
      const long r0 = a_row0 + wr * 128 + mi * 16 + orow;
      const long c0 = b_row0 + wc * 64 + ni * 16 + ocol;
#pragma unroll
      for (int r = 0; r < 4; ++r) C[(r0 + r) * N + c0] = acc[mi][ni][r];
    }
}

// ---------------------------------------------------------------------------
// Launch
// ---------------------------------------------------------------------------
extern "C" void kernel_launch(void* const* d_in, const int* in_sizes, int n_in,
                              void* d_out, int out_size, void* d_ws,
                              size_t ws_size, hipStream_t stream) {
  const float* x = (const float*)d_in[0];
  const float* w = (const float*)d_in[1];
  float* out = (float*)d_out;

  const int K = 4096;
  const long M = (long)in_sizes[0] / K;  // 8192
  const int N = in_sizes[1] / K;         // 4096

  ushort_t* xsp = (ushort_t*)d_ws;      // [M][K] bf16
  ushort_t* wb = xsp + (long)M * K;     // [N][K] bf16

  const long n8x = M * K / 8;
  prune_cast_kernel<<<(int)((n8x + 255) / 256), 256, 0, stream>>>(x, xsp, n8x);

  const long n8w = (long)N * K / 8;
  cast_bf16_kernel<<<(int)((n8w + 255) / 256), 256, 0, stream>>>(w, wb, n8w);

  const int nwg = (int)(M / 256) * (N / 256);  // 512, divisible by 8
  gemm256_kernel<<<nwg, 512, 0, stream>>>(xsp, wb, out, (int)M, N, K);
}

// Round 5
// 446.198 us; speedup vs baseline: 1.1022x; 1.1022x over previous
//
#include <hip/hip_runtime.h>
#include <hip/hip_bf16.h>

typedef float f32x4 __attribute__((ext_vector_type(4)));
typedef __bf16 bf16x8 __attribute__((ext_vector_type(8)));
typedef unsigned short ushort_t;
typedef ushort_t u16x8 __attribute__((ext_vector_type(8)));

// ---------------------------------------------------------------------------
// fp32 -> bf16 round-to-nearest-even
// ---------------------------------------------------------------------------
__device__ inline ushort_t f2bf_rne(float f) {
  unsigned u = __builtin_bit_cast(unsigned, f);
  unsigned r = (u + 0x7fffu + ((u >> 16) & 1u)) >> 16;
  return (ushort_t)r;
}

// ---------------------------------------------------------------------------
// Kernel 1: 2:4 prune (exact fp32 argsort-stable semantics) + cast to bf16.
// ---------------------------------------------------------------------------
__global__ void prune_cast_kernel(const float* __restrict__ x,
                                  ushort_t* __restrict__ xsp, long n8) {
  long i = (long)blockIdx.x * blockDim.x + threadIdx.x;
  if (i >= n8) return;
  const float4* p = reinterpret_cast<const float4*>(x);
  float4 g0 = p[2 * i];
  float4 g1 = p[2 * i + 1];
  float v[8] = {g0.x, g0.y, g0.z, g0.w, g1.x, g1.y, g1.z, g1.w};
  u16x8 o;
#pragma unroll
  for (int g = 0; g < 2; ++g) {
    float a[4];
#pragma unroll
    for (int j = 0; j < 4; ++j) a[j] = fabsf(v[g * 4 + j]);
#pragma unroll
    for (int j = 0; j < 4; ++j) {
      int rank = 0;
#pragma unroll
      for (int k = 0; k < 4; ++k) {
        if (k == j) continue;
        rank += (a[k] < a[j]) || (a[k] == a[j] && k < j);
      }
      o[g * 4 + j] = (rank >= 2) ? f2bf_rne(v[g * 4 + j]) : (ushort_t)0;
    }
  }
  reinterpret_cast<u16x8*>(xsp)[i] = o;
}

// ---------------------------------------------------------------------------
// Kernel 2: fp32 -> bf16 cast of the weight matrix.
// ---------------------------------------------------------------------------
__global__ void cast_bf16_kernel(const float* __restrict__ w,
                                 ushort_t* __restrict__ wb, long n8) {
  long i = (long)blockIdx.x * blockDim.x + threadIdx.x;
  if (i >= n8) return;
  const float4* p = reinterpret_cast<const float4*>(w);
  float4 g0 = p[2 * i];
  float4 g1 = p[2 * i + 1];
  u16x8 o;
  o[0] = f2bf_rne(g0.x); o[1] = f2bf_rne(g0.y);
  o[2] = f2bf_rne(g0.z); o[3] = f2bf_rne(g0.w);
  o[4] = f2bf_rne(g1.x); o[5] = f2bf_rne(g1.y);
  o[6] = f2bf_rne(g1.z); o[7] = f2bf_rne(g1.w);
  reinterpret_cast<u16x8*>(wb)[i] = o;
}

// ---------------------------------------------------------------------------
// Kernel 3: 256x256 8-phase bf16 GEMM.  C[m][n] = sum_k A[m][k]*B[n][k].
// 8 waves (2Mx4N), BK=64, 128 KiB LDS double-buffered, 3-bit XOR swizzle
// (physical chunk = logical chunk ^ (row&7)) -> 0 bank conflicts.
//
// Round-5 schedule: round-3 staging plan (A halves of t+1 into OPPOSITE
// parity at ph0/ph1; B halves of t+2 same parity at ph2/ph3 -- B slots are
// cold there; tile-end vmcnt(4), tail vmcnt(0)) + within-tile ds_read
// pipelining: b23 read one phase early (ph0), afO one phase early (ph1),
// counted lgkmcnt + sched_barrier(0) fences (rule #18).
// ---------------------------------------------------------------------------
#define BAR() __builtin_amdgcn_s_barrier()
#define SCHED0() __builtin_amdgcn_sched_barrier(0)
#define WAIT_LGKM0() asm volatile("s_waitcnt lgkmcnt(0)" ::: "memory")
#define WAIT_LGKM4() asm volatile("s_waitcnt lgkmcnt(4)" ::: "memory")
#define WAIT_LGKM8() asm volatile("s_waitcnt lgkmcnt(8)" ::: "memory")
#define WAIT_VM4() asm volatile("s_waitcnt vmcnt(4)" ::: "memory")
#define WAIT_VM0() asm volatile("s_waitcnt vmcnt(0)" ::: "memory")

#define STAGE_A(t1, h, par)                                                    \
  {                                                                            \
    const ushort_t* g0 =                                                       \
        A + (a_row0 + (h) * 128 + srow) * (long)Kd + (t1) * 64 + scol;         \
    const ushort_t* g1 =                                                       \
        A + (a_row0 + (h) * 128 + srow + 8) * (long)Kd + (t1) * 64 + scol;     \
    ushort_t* l0 = &ldsA[((par) * 2 + (h)) * 8192 + w * 1024];                 \
    __builtin_amdgcn_global_load_lds(                                          \
        (const __attribute__((address_space(1))) void*)g0,                     \
        (__attribute__((address_space(3))) void*)l0, 16, 0, 0);                \
    __builtin_amdgcn_global_load_lds(                                          \
        (const __attribute__((address_space(1))) void*)g1,                     \
        (__attribute__((address_space(3))) void*)(l0 + 512), 16, 0, 0);        \
  }

#define STAGE_B(t1, h, par)                                                    \
  {                                                                            \
    const ushort_t* g0 =                                                       \
        B + (b_row0 + (h) * 128 + srow) * (long)Kd + (t1) * 64 + scol;         \
    const ushort_t* g1 =                                                       \
        B + (b_row0 + (h) * 128 + srow + 8) * (long)Kd + (t1) * 64 + scol;     \
    ushort_t* l0 = &ldsB[((par) * 2 + (h)) * 8192 + w * 1024];                 \
    __builtin_amdgcn_global_load_lds(                                          \
        (const __attribute__((address_space(1))) void*)g0,                     \
        (__attribute__((address_space(3))) void*)l0, 16, 0, 0);                \
    __builtin_amdgcn_global_load_lds(                                          \
        (const __attribute__((address_space(1))) void*)g1,                     \
        (__attribute__((address_space(3))) void*)(l0 + 512), 16, 0, 0);        \
  }

#define LDA_FRAG(dst, par, mi, s)                                              \
  dst = *reinterpret_cast<const bf16x8*>(                                      \
      reinterpret_cast<const char*>(ldsA) + ((par) * 2 + wr) * 16384 +         \
      (mi) * 2048 + ((s) ? roff1 : roff0));

#define LDB_FRAG(dst, par, ni, s)                                              \
  dst = *reinterpret_cast<const bf16x8*>(                                      \
      reinterpret_cast<const char*>(ldsB) + ((par) * 2 + (wc >> 1)) * 16384 +  \
      (wc & 1) * 8192 + (ni) * 2048 + ((s) ? roff1 : roff0));

#define MFMA_Q(AF, BF, MH, NH)                                                 \
  __builtin_amdgcn_s_setprio(1);                                               \
  _Pragma("unroll") for (int s = 0; s < 2; ++s)                                \
  _Pragma("unroll") for (int mi = 0; mi < 4; ++mi)                             \
  _Pragma("unroll") for (int ni = 0; ni < 2; ++ni)                             \
      acc[(MH) * 4 + mi][(NH) * 2 + ni] =                                      \
          __builtin_amdgcn_mfma_f32_16x16x32_bf16(                             \
              AF[mi][s], BF[ni][s], acc[(MH) * 4 + mi][(NH) * 2 + ni],         \
              0, 0, 0);                                                        \
  __builtin_amdgcn_s_setprio(0);

#define KTILE(t, PAR)                                                          \
  { /* ph0: read afE+b01 (this phase) + b23 (lookahead); stage A0(t+1,op) */   \
    _Pragma("unroll") for (int mi = 0; mi < 4; ++mi)                           \
    _Pragma("unroll") for (int s = 0; s < 2; ++s)                              \
        LDA_FRAG(afE[mi][s], PAR, mi, s)                                       \
    _Pragma("unroll") for (int ni = 0; ni < 2; ++ni)                           \
    _Pragma("unroll") for (int s = 0; s < 2; ++s)                              \
        LDB_FRAG(b01[ni][s], PAR, ni, s)                                       \
    _Pragma("unroll") for (int ni = 0; ni < 2; ++ni)                           \
    _Pragma("unroll") for (int s = 0; s < 2; ++s)                              \
        LDB_FRAG(b23[ni][s], PAR, 2 + ni, s)                                   \
    if ((t) + 1 < NT) STAGE_A((t) + 1, 0, (PAR) ^ 1)                           \
    BAR();                                                                     \
    WAIT_LGKM4();                                                              \
    SCHED0();                                                                  \
    MFMA_Q(afE, b01, 0, 0)                                                     \
    BAR();                                                                     \
    /* ph1: read afO (lookahead); stage A1(t+1,op); MFMA Q(0,1) (b23) */       \
    _Pragma("unroll") for (int mi = 0; mi < 4; ++mi)                           \
    _Pragma("unroll") for (int s = 0; s < 2; ++s)                              \
        LDA_FRAG(afO[mi][s], PAR, 4 + mi, s)                                   \
    if ((t) + 1 < NT) STAGE_A((t) + 1, 1, (PAR) ^ 1)                           \
    BAR();                                                                     \
    WAIT_LGKM8();                                                              \
    SCHED0();                                                                  \
    MFMA_Q(afE, b23, 0, 1)                                                     \
    BAR();                                                                     \
    /* ph2: stage B0(t+2, same par -- B slots cold); MFMA Q(1,1) (afO) */      \
    if ((t) + 2 < NT) STAGE_B((t) + 2, 0, PAR)                                 \
    BAR();                                                                     \
    WAIT_LGKM0();                                                              \
    SCHED0();                                                                  \
    MFMA_Q(afO, b23, 1, 1)                                                     \
    BAR();                                                                     \
    /* ph3: stage B1(t+2); MFMA Q(1,0); tile-end wait */                       \
    if ((t) + 2 < NT) STAGE_B((t) + 2, 1, PAR)                                 \
    BAR();                                                                     \
    MFMA_Q(afO, b01, 1, 0)                                                     \
    if ((t) + 2 < NT) { WAIT_VM4(); } else { WAIT_VM0(); }                     \
    BAR();                                                                     \
  }

__global__ __launch_bounds__(512, 1) void gemm256_kernel(
    const ushort_t* __restrict__ A,  // [M][K] bf16 (pruned x)
    const ushort_t* __restrict__ B,  // [N][K] bf16 (weight)
    float* __restrict__ C,           // [M][N] fp32
    int M, int N, int Kd) {
  __shared__ ushort_t ldsA[4 * 8192];  // 4 slots x 16 KiB (par,half)
  __shared__ ushort_t ldsB[4 * 8192];

  const int tid = threadIdx.x;
  const int lane = tid & 63;
  const int w = tid >> 6;   // wave 0..7
  const int wr = w >> 2;    // 0..1 -> 128-row half
  const int wc = w & 3;     // 0..3 -> 64-col slab

  // XCD-bijective grid swizzle (gridDim.x % 8 == 0)
  const int b = blockIdx.x;
  const int wg = (b & 7) * (gridDim.x >> 3) + (b >> 3);
  const int nbn = N / 256;
  const int bm = wg / nbn, bn = wg % nbn;
  const long a_row0 = (long)bm * 256;
  const long b_row0 = (long)bn * 256;
  const int NT = Kd / 64;

  // staging: instr i of wave w, lane l writes LINEAR physical (row
  // 16w+8i+(l>>3), chunk l&7); swizzle physical(r,c) <- logical(r, c^(r&7))
  // -> global SOURCE chunk = (l&7) ^ ((l>>3)&7)  (same for both instrs).
  const int srow = w * 16 + (lane >> 3);
  const int scol = (((lane & 7) ^ ((lane >> 3) & 7)) << 3);  // ushort units

  // fragment read: logical (row rl, chunk q|s<<2) -> physical chunk
  // (q|s<<2) ^ (rl&7); s folded inside the XOR -> two precomputed offsets.
  const int rl = lane & 15;
  const int q = lane >> 4;
  const int roff0 = rl * 128 + (((q) ^ (rl & 7)) << 4);
  const int roff1 = rl * 128 + (((q | 4) ^ (rl & 7)) << 4);

  f32x4 acc[8][4];
#pragma unroll
  for (int i = 0; i < 8; ++i)
#pragma unroll
    for (int j = 0; j < 4; ++j) acc[i][j] = f32x4{0.f, 0.f, 0.f, 0.f};

  bf16x8 afE[4][2];  // A-mh0 fragments (read ph0)
  bf16x8 afO[4][2];  // A-mh1 fragments (lookahead read ph1)
  bf16x8 b01[2][2];  // B n0..1 fragments (read ph0)
  bf16x8 b23[2][2];  // B n2..3 fragments (lookahead read ph0)

  // ---- prologue: stage tile 0 (par0) fully + A of tile 1 (par1); tile 1's
  // B halves get staged during tile 0 (ph2/ph3). vmcnt(4): tile-0 landed. ----
  STAGE_A(0, 0, 0)
  STAGE_A(0, 1, 0)
  STAGE_B(0, 0, 0)
  STAGE_B(0, 1, 0)
  STAGE_B(1, 0, 1)
  STAGE_B(1, 1, 1)
  WAIT_VM4();
  BAR();

  for (int t = 0; t < NT; t += 2) {
    KTILE(t, 0)
    KTILE(t + 1, 1)
  }

  // ---- epilogue: C/D layout col=lane&15, row=(lane>>4)*4+r ----
  const int orow = (lane >> 4) * 4;
  const int ocol = lane & 15;
#pragma unroll
  for (int mi = 0; mi < 8; ++mi)
#pragma unroll
    for (int ni = 0; ni < 4; ++ni) {
      const long r0 = a_row0 + wr * 128 + mi * 16 + orow;
      const long c0 = b_row0 + wc * 64 + ni * 16 + ocol;
#pragma unroll
      for (int r = 0; r < 4; ++r) C[(r0 + r) * N + c0] = acc[mi][ni][r];
    }
}

// ---------------------------------------------------------------------------
// Launch
// ---------------------------------------------------------------------------
extern "C" void kernel_launch(void* const* d_in, const int* in_sizes, int n_in,
                              void* d_out, int out_size, void* d_ws,
                              size_t ws_size, hipStream_t stream) {
  const float* x = (const float*)d_in[0];
  const float* w = (const float*)d_in[1];
  float* out = (float*)d_out;

  const int K = 4096;
  const long M = (long)in_sizes[0] / K;  // 8192
  const int N = in_sizes[1] / K;         // 4096

  ushort_t* xsp = (ushort_t*)d_ws;      // [M][K] bf16
  ushort_t* wb = xsp + (long)M * K;     // [N][K] bf16

  const long n8x = M * K / 8;
  prune_cast_kernel<<<(int)((n8x + 255) / 256), 256, 0, stream>>>(x, xsp, n8x);

  const long n8w = (long)N * K / 8;
  cast_bf16_kernel<<<(int)((n8w + 255) / 256), 256, 0, stream>>>(w, wb, n8w);

  const int nwg = (int)(M / 256) * (N / 256);  // 512, divisible by 8
  gemm256_kernel<<<nwg, 512, 0, stream>>>(xsp, wb, out, (int)M, N, K);
}

// Round 6
// 289.528 us; speedup vs baseline: 1.6986x; 1.5411x over previous
//
#include <hip/hip_runtime.h>
#include <hip/hip_bf16.h>

typedef float f32x4 __attribute__((ext_vector_type(4)));
typedef __bf16 bf16x8 __attribute__((ext_vector_type(8)));
typedef unsigned short ushort_t;
typedef ushort_t u16x8 __attribute__((ext_vector_type(8)));

// ---------------------------------------------------------------------------
// fp32 -> bf16 round-to-nearest-even
// ---------------------------------------------------------------------------
__device__ inline ushort_t f2bf_rne(float f) {
  unsigned u = __builtin_bit_cast(unsigned, f);
  unsigned r = (u + 0x7fffu + ((u >> 16) & 1u)) >> 16;
  return (ushort_t)r;
}

// ---------------------------------------------------------------------------
// Kernel 1: 2:4 prune (exact fp32 argsort-stable semantics) + cast to bf16.
// ---------------------------------------------------------------------------
__global__ void prune_cast_kernel(const float* __restrict__ x,
                                  ushort_t* __restrict__ xsp, long n8) {
  long i = (long)blockIdx.x * blockDim.x + threadIdx.x;
  if (i >= n8) return;
  const float4* p = reinterpret_cast<const float4*>(x);
  float4 g0 = p[2 * i];
  float4 g1 = p[2 * i + 1];
  float v[8] = {g0.x, g0.y, g0.z, g0.w, g1.x, g1.y, g1.z, g1.w};
  u16x8 o;
#pragma unroll
  for (int g = 0; g < 2; ++g) {
    float a[4];
#pragma unroll
    for (int j = 0; j < 4; ++j) a[j] = fabsf(v[g * 4 + j]);
#pragma unroll
    for (int j = 0; j < 4; ++j) {
      int rank = 0;
#pragma unroll
      for (int k = 0; k < 4; ++k) {
        if (k == j) continue;
        rank += (a[k] < a[j]) || (a[k] == a[j] && k < j);
      }
      o[g * 4 + j] = (rank >= 2) ? f2bf_rne(v[g * 4 + j]) : (ushort_t)0;
    }
  }
  reinterpret_cast<u16x8*>(xsp)[i] = o;
}

// ---------------------------------------------------------------------------
// Kernel 2: fp32 -> bf16 cast of the weight matrix.
// ---------------------------------------------------------------------------
__global__ void cast_bf16_kernel(const float* __restrict__ w,
                                 ushort_t* __restrict__ wb, long n8) {
  long i = (long)blockIdx.x * blockDim.x + threadIdx.x;
  if (i >= n8) return;
  const float4* p = reinterpret_cast<const float4*>(w);
  float4 g0 = p[2 * i];
  float4 g1 = p[2 * i + 1];
  u16x8 o;
  o[0] = f2bf_rne(g0.x); o[1] = f2bf_rne(g0.y);
  o[2] = f2bf_rne(g0.z); o[3] = f2bf_rne(g0.w);
  o[4] = f2bf_rne(g1.x); o[5] = f2bf_rne(g1.y);
  o[6] = f2bf_rne(g1.z); o[7] = f2bf_rne(g1.w);
  reinterpret_cast<u16x8*>(wb)[i] = o;
}

// ---------------------------------------------------------------------------
// Kernel 3: 256x256 8-phase bf16 GEMM.  C[m][n] = sum_k A[m][k]*B[n][k].
// 8 waves (2Mx4N), BK=64, 128 KiB LDS double-buffered, 3-bit XOR swizzle
// (physical chunk = logical chunk ^ (row&7)) -> 0 bank conflicts.
//
// Round-6: round-3 schedule/registers (A(t+1) opposite parity ph0/ph1,
// B(t+2) same parity ph2/ph3, tile-end vmcnt(4), tail vmcnt(0)), but NO
// forced lgkmcnt(0) drains: ds_reads are compiler-visible loads, so the
// compiler emits fine-grained counted lgkmcnt before each dependent MFMA.
// Reads are issue-ordered for earliest consumption; MFMA loop order matches.
// ---------------------------------------------------------------------------
#define BAR() __builtin_amdgcn_s_barrier()
#define WAIT_VM4() asm volatile("s_waitcnt vmcnt(4)" ::: "memory")
#define WAIT_VM0() asm volatile("s_waitcnt vmcnt(0)" ::: "memory")

#define STAGE_A(t1, h, par)                                                    \
  {                                                                            \
    const ushort_t* g0 =                                                       \
        A + (a_row0 + (h) * 128 + srow) * (long)Kd + (t1) * 64 + scol;         \
    const ushort_t* g1 =                                                       \
        A + (a_row0 + (h) * 128 + srow + 8) * (long)Kd + (t1) * 64 + scol;     \
    ushort_t* l0 = &ldsA[((par) * 2 + (h)) * 8192 + w * 1024];                 \
    __builtin_amdgcn_global_load_lds(                                          \
        (const __attribute__((address_space(1))) void*)g0,                     \
        (__attribute__((address_space(3))) void*)l0, 16, 0, 0);                \
    __builtin_amdgcn_global_load_lds(                                          \
        (const __attribute__((address_space(1))) void*)g1,                     \
        (__attribute__((address_space(3))) void*)(l0 + 512), 16, 0, 0);        \
  }

#define STAGE_B(t1, h, par)                                                    \
  {                                                                            \
    const ushort_t* g0 =                                                       \
        B + (b_row0 + (h) * 128 + srow) * (long)Kd + (t1) * 64 + scol;         \
    const ushort_t* g1 =                                                       \
        B + (b_row0 + (h) * 128 + srow + 8) * (long)Kd + (t1) * 64 + scol;     \
    ushort_t* l0 = &ldsB[((par) * 2 + (h)) * 8192 + w * 1024];                 \
    __builtin_amdgcn_global_load_lds(                                          \
        (const __attribute__((address_space(1))) void*)g0,                     \
        (__attribute__((address_space(3))) void*)l0, 16, 0, 0);                \
    __builtin_amdgcn_global_load_lds(                                          \
        (const __attribute__((address_space(1))) void*)g1,                     \
        (__attribute__((address_space(3))) void*)(l0 + 512), 16, 0, 0);        \
  }

#define LDA_FRAG(dst, par, mi, s)                                              \
  dst = *reinterpret_cast<const bf16x8*>(                                      \
      reinterpret_cast<const char*>(ldsA) + ((par) * 2 + wr) * 16384 +         \
      (mi) * 2048 + ((s) ? roff1 : roff0));

#define LDB_FRAG(dst, par, ni, s)                                              \
  dst = *reinterpret_cast<const bf16x8*>(                                      \
      reinterpret_cast<const char*>(ldsB) + ((par) * 2 + (wc >> 1)) * 16384 +  \
      (wc & 1) * 8192 + (ni) * 2048 + ((s) ? roff1 : roff0));

// mi-outer MFMA cluster: consumes af[mi] in read-issue order.
#define MFMA_Q(MH, NH)                                                         \
  __builtin_amdgcn_s_setprio(1);                                               \
  _Pragma("unroll") for (int mi = 0; mi < 4; ++mi)                             \
  _Pragma("unroll") for (int s = 0; s < 2; ++s)                                \
  _Pragma("unroll") for (int ni = 0; ni < 2; ++ni)                             \
      acc[(MH) * 4 + mi][(NH) * 2 + ni] =                                      \
          __builtin_amdgcn_mfma_f32_16x16x32_bf16(                             \
              af[mi][s], bfr[(NH) * 2 + ni][s],                                \
              acc[(MH) * 4 + mi][(NH) * 2 + ni], 0, 0, 0);                     \
  __builtin_amdgcn_s_setprio(0);

// ni-outer MFMA cluster: consumes bfr[2],bfr[3] in read-issue order.
#define MFMA_QN(MH, NH)                                                        \
  __builtin_amdgcn_s_setprio(1);                                               \
  _Pragma("unroll") for (int ni = 0; ni < 2; ++ni)                             \
  _Pragma("unroll") for (int s = 0; s < 2; ++s)                                \
  _Pragma("unroll") for (int mi = 0; mi < 4; ++mi)                             \
      acc[(MH) * 4 + mi][(NH) * 2 + ni] =                                      \
          __builtin_amdgcn_mfma_f32_16x16x32_bf16(                             \
              af[mi][s], bfr[(NH) * 2 + ni][s],                                \
              acc[(MH) * 4 + mi][(NH) * 2 + ni], 0, 0, 0);                     \
  __builtin_amdgcn_s_setprio(0);

#define KTILE(t, PAR)                                                          \
  { /* ph0: reads ordered af0,b01,af1..3 ; stage A0(t+1,op) ; MFMA Q(0,0) */   \
    LDA_FRAG(af[0][0], PAR, 0, 0)                                              \
    LDA_FRAG(af[0][1], PAR, 0, 1)                                              \
    LDB_FRAG(bfr[0][0], PAR, 0, 0)                                             \
    LDB_FRAG(bfr[0][1], PAR, 0, 1)                                             \
    LDB_FRAG(bfr[1][0], PAR, 1, 0)                                             \
    LDB_FRAG(bfr[1][1], PAR, 1, 1)                                             \
    LDA_FRAG(af[1][0], PAR, 1, 0)                                              \
    LDA_FRAG(af[1][1], PAR, 1, 1)                                              \
    LDA_FRAG(af[2][0], PAR, 2, 0)                                              \
    LDA_FRAG(af[2][1], PAR, 2, 1)                                              \
    LDA_FRAG(af[3][0], PAR, 3, 0)                                              \
    LDA_FRAG(af[3][1], PAR, 3, 1)                                              \
    if ((t) + 1 < NT) STAGE_A((t) + 1, 0, (PAR) ^ 1)                           \
    BAR();                                                                     \
    MFMA_Q(0, 0)                                                               \
    BAR();                                                                     \
    /* ph1: read b23 ; stage A1(t+1,op) ; MFMA Q(0,1) ni-outer */              \
    LDB_FRAG(bfr[2][0], PAR, 2, 0)                                             \
    LDB_FRAG(bfr[2][1], PAR, 2, 1)                                             \
    LDB_FRAG(bfr[3][0], PAR, 3, 0)                                             \
    LDB_FRAG(bfr[3][1], PAR, 3, 1)                                             \
    if ((t) + 1 < NT) STAGE_A((t) + 1, 1, (PAR) ^ 1)                           \
    BAR();                                                                     \
    MFMA_QN(0, 1)                                                              \
    BAR();                                                                     \
    /* ph2: read af (mh1) ; stage B0(t+2, same par) ; MFMA Q(1,1) */           \
    _Pragma("unroll") for (int mi = 0; mi < 4; ++mi)                           \
    _Pragma("unroll") for (int s = 0; s < 2; ++s)                              \
        LDA_FRAG(af[mi][s], PAR, 4 + mi, s)                                    \
    if ((t) + 2 < NT) STAGE_B((t) + 2, 0, PAR)                                 \
    BAR();                                                                     \
    MFMA_Q(1, 1)                                                               \
    BAR();                                                                     \
    /* ph3: stage B1(t+2) ; MFMA Q(1,0) ; tile-end wait */                     \
    if ((t) + 2 < NT) STAGE_B((t) + 2, 1, PAR)                                 \
    BAR();                                                                     \
    MFMA_Q(1, 0)                                                               \
    if ((t) + 2 < NT) { WAIT_VM4(); } else { WAIT_VM0(); }                     \
    BAR();                                                                     \
  }

__global__ __launch_bounds__(512, 1) void gemm256_kernel(
    const ushort_t* __restrict__ A,  // [M][K] bf16 (pruned x)
    const ushort_t* __restrict__ B,  // [N][K] bf16 (weight)
    float* __restrict__ C,           // [M][N] fp32
    int M, int N, int Kd) {
  __shared__ ushort_t ldsA[4 * 8192];  // 4 slots x 16 KiB (par,half)
  __shared__ ushort_t ldsB[4 * 8192];

  const int tid = threadIdx.x;
  const int lane = tid & 63;
  const int w = tid >> 6;   // wave 0..7
  const int wr = w >> 2;    // 0..1 -> 128-row half
  const int wc = w & 3;     // 0..3 -> 64-col slab

  // XCD-bijective grid swizzle (gridDim.x % 8 == 0)
  const int b = blockIdx.x;
  const int wg = (b & 7) * (gridDim.x >> 3) + (b >> 3);
  const int nbn = N / 256;
  const int bm = wg / nbn, bn = wg % nbn;
  const long a_row0 = (long)bm * 256;
  const long b_row0 = (long)bn * 256;
  const int NT = Kd / 64;

  // staging: instr i of wave w, lane l writes LINEAR physical (row
  // 16w+8i+(l>>3), chunk l&7); swizzle physical(r,c) <- logical(r, c^(r&7))
  // -> global SOURCE chunk = (l&7) ^ ((l>>3)&7)  (same for both instrs).
  const int srow = w * 16 + (lane >> 3);
  const int scol = (((lane & 7) ^ ((lane >> 3) & 7)) << 3);  // ushort units

  // fragment read: logical (row rl, chunk q|s<<2) -> physical chunk
  // (q|s<<2) ^ (rl&7); s folded inside the XOR -> two precomputed offsets.
  const int rl = lane & 15;
  const int q = lane >> 4;
  const int roff0 = rl * 128 + (((q) ^ (rl & 7)) << 4);
  const int roff1 = rl * 128 + (((q | 4) ^ (rl & 7)) << 4);

  f32x4 acc[8][4];
#pragma unroll
  for (int i = 0; i < 8; ++i)
#pragma unroll
    for (int j = 0; j < 4; ++j) acc[i][j] = f32x4{0.f, 0.f, 0.f, 0.f};

  bf16x8 af[4][2];   // A fragments (reused mh0 in ph0/ph1, mh1 in ph2/ph3)
  bf16x8 bfr[4][2];  // all 4 n fragments (persistent across the tile)

  // ---- prologue: stage tile 0 (par0) fully + B of tile 1 (par1); tile 1's
  // A halves get staged during tile 0 (ph0/ph1). vmcnt(4): tile-0 landed. ----
  STAGE_A(0, 0, 0)
  STAGE_A(0, 1, 0)
  STAGE_B(0, 0, 0)
  STAGE_B(0, 1, 0)
  STAGE_B(1, 0, 1)
  STAGE_B(1, 1, 1)
  WAIT_VM4();
  BAR();

  for (int t = 0; t < NT; t += 2) {
    KTILE(t, 0)
    KTILE(t + 1, 1)
  }

  // ---- epilogue: C/D layout col=lane&15, row=(lane>>4)*4+r ----
  const int orow = (lane >> 4) * 4;
  const int ocol = lane & 15;
#pragma unroll
  for (int mi = 0; mi < 8; ++mi)
#pragma unroll
    for (int ni = 0; ni < 4; ++ni) {
      const long r0 = a_row0 + wr * 128 + mi * 16 + orow;
      const long c0 = b_row0 + wc * 64 + ni * 16 + ocol;
#pragma unroll
      for (int r = 0; r < 4; ++r) C[(r0 + r) * N + c0] = acc[mi][ni][r];
    }
}

// ---------------------------------------------------------------------------
// Launch
// ---------------------------------------------------------------------------
extern "C" void kernel_launch(void* const* d_in, const int* in_sizes, int n_in,
                              void* d_out, int out_size, void* d_ws,
                              size_t ws_size, hipStream_t stream) {
  const float* x = (const float*)d_in[0];
  const float* w = (const float*)d_in[1];
  float* out = (float*)d_out;

  const int K = 4096;
  const long M = (long)in_sizes[0] / K;  // 8192
  const int N = in_sizes[1] / K;         // 4096

  ushort_t* xsp = (ushort_t*)d_ws;      // [M][K] bf16
  ushort_t* wb = xsp + (long)M * K;     // [N][K] bf16

  const long n8x = M * K / 8;
  prune_cast_kernel<<<(int)((n8x + 255) / 256), 256, 0, stream>>>(x, xsp, n8x);

  const long n8w = (long)N * K / 8;
  cast_bf16_kernel<<<(int)((n8w + 255) / 256), 256, 0, stream>>>(w, wb, n8w);

  const int nwg = (int)(M / 256) * (N / 256);  // 512, divisible by 8
  gemm256_kernel<<<nwg, 512, 0, stream>>>(xsp, wb, out, (int)M, N, K);
}

// Round 7
// 267.438 us; speedup vs baseline: 1.8389x; 1.0826x over previous
//
#include <hip/hip_runtime.h>
#include <hip/hip_bf16.h>

typedef float f32x4 __attribute__((ext_vector_type(4)));
typedef __bf16 bf16x8 __attribute__((ext_vector_type(8)));
typedef unsigned short ushort_t;
typedef ushort_t u16x8 __attribute__((ext_vector_type(8)));

// ---------------------------------------------------------------------------
// fp32 -> bf16 round-to-nearest-even
// ---------------------------------------------------------------------------
__device__ inline ushort_t f2bf_rne(float f) {
  unsigned u = __builtin_bit_cast(unsigned, f);
  unsigned r = (u + 0x7fffu + ((u >> 16) & 1u)) >> 16;
  return (ushort_t)r;
}

// ---------------------------------------------------------------------------
// Kernel 1: 2:4 prune (exact fp32 argsort-stable semantics) + cast to bf16.
// ---------------------------------------------------------------------------
__global__ void prune_cast_kernel(const float* __restrict__ x,
                                  ushort_t* __restrict__ xsp, long n8) {
  long i = (long)blockIdx.x * blockDim.x + threadIdx.x;
  if (i >= n8) return;
  const float4* p = reinterpret_cast<const float4*>(x);
  float4 g0 = p[2 * i];
  float4 g1 = p[2 * i + 1];
  float v[8] = {g0.x, g0.y, g0.z, g0.w, g1.x, g1.y, g1.z, g1.w};
  u16x8 o;
#pragma unroll
  for (int g = 0; g < 2; ++g) {
    float a[4];
#pragma unroll
    for (int j = 0; j < 4; ++j) a[j] = fabsf(v[g * 4 + j]);
#pragma unroll
    for (int j = 0; j < 4; ++j) {
      int rank = 0;
#pragma unroll
      for (int k = 0; k < 4; ++k) {
        if (k == j) continue;
        rank += (a[k] < a[j]) || (a[k] == a[j] && k < j);
      }
      o[g * 4 + j] = (rank >= 2) ? f2bf_rne(v[g * 4 + j]) : (ushort_t)0;
    }
  }
  reinterpret_cast<u16x8*>(xsp)[i] = o;
}

// ---------------------------------------------------------------------------
// Kernel 2: fp32 -> bf16 cast of the weight matrix.
// ---------------------------------------------------------------------------
__global__ void cast_bf16_kernel(const float* __restrict__ w,
                                 ushort_t* __restrict__ wb, long n8) {
  long i = (long)blockIdx.x * blockDim.x + threadIdx.x;
  if (i >= n8) return;
  const float4* p = reinterpret_cast<const float4*>(w);
  float4 g0 = p[2 * i];
  float4 g1 = p[2 * i + 1];
  u16x8 o;
  o[0] = f2bf_rne(g0.x); o[1] = f2bf_rne(g0.y);
  o[2] = f2bf_rne(g0.z); o[3] = f2bf_rne(g0.w);
  o[4] = f2bf_rne(g1.x); o[5] = f2bf_rne(g1.y);
  o[6] = f2bf_rne(g1.z); o[7] = f2bf_rne(g1.w);
  reinterpret_cast<u16x8*>(wb)[i] = o;
}

// ---------------------------------------------------------------------------
// Kernel 3: 256x256 bf16 GEMM, TWO barriers per K-tile.
// C[m][n] = sum_k A[m][k]*B[n][k].  8 waves (2Mx4N), BK=64, 128 KiB LDS
// double-buffered, 3-bit XOR swizzle (physical chunk = logical ^ (row&7))
// -> 0 bank conflicts.
//
// Round-7 theory: rounds 3/6 serialized the LDS pipe and the MFMA pipe at CU
// level (burst-read / barrier / burst-MFMA convoy, 8x per tile).  Only two
// barriers are structurally required per tile:
//   mid-BAR : all waves' B-fragment reads DELIVERED (implied by MFMA
//             consumption in Q(0,0)/Q(0,1)/Q(1,1)) before any wave issues
//             stage_B(t+2) into the same-parity B slots.
//   end-BAR : after per-wave vmcnt(4) -> every wave's A(t+1)/B(t+1) stage
//             loads have landed before any wave reads them in tile t+1.
// Everything else (reads, stages, 64 MFMAs) lives in one region where the
// compiler's counted lgkmcnt + natural wave drift overlap the two pipes.
// A-stage safety: A(t+1) targets the OPPOSITE parity, whose reads were all
// consumed before tile (t-1)'s end barrier.
// Branch-free tail: stage indices clamp to NT-1 (junk lands in slots whose
// reads are already delivered and never re-read).
// ---------------------------------------------------------------------------
#define BARM()                              \
  asm volatile("" ::: "memory");            \
  __builtin_amdgcn_s_barrier();             \
  asm volatile("" ::: "memory");
#define WAIT_VM4() asm volatile("s_waitcnt vmcnt(4)" ::: "memory")
#define WAIT_VM0() asm volatile("s_waitcnt vmcnt(0)" ::: "memory")

#define STAGE_A(t1, h, par)                                                    \
  {                                                                            \
    const ushort_t* g0 =                                                       \
        A + (a_row0 + (h) * 128 + srow) * (long)Kd + (t1) * 64 + scol;         \
    const ushort_t* g1 =                                                       \
        A + (a_row0 + (h) * 128 + srow + 8) * (long)Kd + (t1) * 64 + scol;     \
    ushort_t* l0 = &ldsA[((par) * 2 + (h)) * 8192 + w * 1024];                 \
    __builtin_amdgcn_global_load_lds(                                          \
        (const __attribute__((address_space(1))) void*)g0,                     \
        (__attribute__((address_space(3))) void*)l0, 16, 0, 0);                \
    __builtin_amdgcn_global_load_lds(                                          \
        (const __attribute__((address_space(1))) void*)g1,                     \
        (__attribute__((address_space(3))) void*)(l0 + 512), 16, 0, 0);        \
  }

#define STAGE_B(t1, h, par)                                                    \
  {                                                                            \
    const ushort_t* g0 =                                                       \
        B + (b_row0 + (h) * 128 + srow) * (long)Kd + (t1) * 64 + scol;         \
    const ushort_t* g1 =                                                       \
        B + (b_row0 + (h) * 128 + srow + 8) * (long)Kd + (t1) * 64 + scol;     \
    ushort_t* l0 = &ldsB[((par) * 2 + (h)) * 8192 + w * 1024];                 \
    __builtin_amdgcn_global_load_lds(                                          \
        (const __attribute__((address_space(1))) void*)g0,                     \
        (__attribute__((address_space(3))) void*)l0, 16, 0, 0);                \
    __builtin_amdgcn_global_load_lds(                                          \
        (const __attribute__((address_space(1))) void*)g1,                     \
        (__attribute__((address_space(3))) void*)(l0 + 512), 16, 0, 0);        \
  }

#define LDA_FRAG(dst, par, mi, s)                                              \
  dst = *reinterpret_cast<const bf16x8*>(                                      \
      reinterpret_cast<const char*>(ldsA) + ((par) * 2 + wr) * 16384 +         \
      (mi) * 2048 + ((s) ? roff1 : roff0));

#define LDB_FRAG(dst, par, ni, s)                                              \
  dst = *reinterpret_cast<const bf16x8*>(                                      \
      reinterpret_cast<const char*>(ldsB) + ((par) * 2 + (wc >> 1)) * 16384 +  \
      (wc & 1) * 8192 + (ni) * 2048 + ((s) ? roff1 : roff0));

// s-outer: distance 8 between dependent updates of the same acc register.
#define MFMA_Q(MH, NH)                                                         \
  __builtin_amdgcn_s_setprio(1);                                               \
  _Pragma("unroll") for (int s = 0; s < 2; ++s)                                \
  _Pragma("unroll") for (int mi = 0; mi < 4; ++mi)                             \
  _Pragma("unroll") for (int ni = 0; ni < 2; ++ni)                             \
      acc[(MH) * 4 + mi][(NH) * 2 + ni] =                                      \
          __builtin_amdgcn_mfma_f32_16x16x32_bf16(                             \
              af[mi][s], bfr[(NH) * 2 + ni][s],                                \
              acc[(MH) * 4 + mi][(NH) * 2 + ni], 0, 0, 0);                     \
  __builtin_amdgcn_s_setprio(0);

#define KTILE(t, PAR)                                                          \
  {                                                                            \
    const int tA = ((t) + 1 < NT) ? (t) + 1 : NT - 1;                          \
    const int tB = ((t) + 2 < NT) ? (t) + 2 : NT - 1;                          \
    /* region 1: reads + A-stage + 48 MFMAs, one barrier-free region */        \
    _Pragma("unroll") for (int mi = 0; mi < 4; ++mi)                           \
    _Pragma("unroll") for (int s = 0; s < 2; ++s)                              \
        LDA_FRAG(af[mi][s], PAR, mi, s)                                        \
    _Pragma("unroll") for (int ni = 0; ni < 4; ++ni)                           \
    _Pragma("unroll") for (int s = 0; s < 2; ++s)                              \
        LDB_FRAG(bfr[ni][s], PAR, ni, s)                                       \
    STAGE_A(tA, 0, (PAR) ^ 1)                                                  \
    STAGE_A(tA, 1, (PAR) ^ 1)                                                  \
    MFMA_Q(0, 0)                                                               \
    MFMA_Q(0, 1)                                                               \
    _Pragma("unroll") for (int mi = 0; mi < 4; ++mi)                           \
    _Pragma("unroll") for (int s = 0; s < 2; ++s)                              \
        LDA_FRAG(af[mi][s], PAR, 4 + mi, s)                                    \
    MFMA_Q(1, 1)                                                               \
    /* all B reads delivered (consumed above) on every wave */                 \
    BARM()                                                                     \
    STAGE_B(tB, 0, PAR)                                                        \
    STAGE_B(tB, 1, PAR)                                                        \
    MFMA_Q(1, 0)                                                               \
    WAIT_VM4();                                                                \
    BARM()                                                                     \
  }

__global__ __launch_bounds__(512, 1) void gemm256_kernel(
    const ushort_t* __restrict__ A,  // [M][K] bf16 (pruned x)
    const ushort_t* __restrict__ B,  // [N][K] bf16 (weight)
    float* __restrict__ C,           // [M][N] fp32
    int M, int N, int Kd) {
  __shared__ ushort_t ldsA[4 * 8192];  // 4 slots x 16 KiB (par,half)
  __shared__ ushort_t ldsB[4 * 8192];

  const int tid = threadIdx.x;
  const int lane = tid & 63;
  const int w = tid >> 6;   // wave 0..7
  const int wr = w >> 2;    // 0..1 -> 128-row half
  const int wc = w & 3;     // 0..3 -> 64-col slab

  // XCD-bijective grid swizzle (gridDim.x % 8 == 0)
  const int b = blockIdx.x;
  const int wg = (b & 7) * (gridDim.x >> 3) + (b >> 3);
  const int nbn = N / 256;
  const int bm = wg / nbn, bn = wg % nbn;
  const long a_row0 = (long)bm * 256;
  const long b_row0 = (long)bn * 256;
  const int NT = Kd / 64;

  // staging: instr i of wave w, lane l writes LINEAR physical (row
  // 16w+8i+(l>>3), chunk l&7); swizzle physical(r,c) <- logical(r, c^(r&7))
  // -> global SOURCE chunk = (l&7) ^ ((l>>3)&7)  (same for both instrs).
  const int srow = w * 16 + (lane >> 3);
  const int scol = (((lane & 7) ^ ((lane >> 3) & 7)) << 3);  // ushort units

  // fragment read: logical (row rl, chunk q|s<<2) -> physical chunk
  // (q|s<<2) ^ (rl&7); s folded inside the XOR -> two precomputed offsets.
  const int rl = lane & 15;
  const int q = lane >> 4;
  const int roff0 = rl * 128 + (((q) ^ (rl & 7)) << 4);
  const int roff1 = rl * 128 + (((q | 4) ^ (rl & 7)) << 4);

  f32x4 acc[8][4];
#pragma unroll
  for (int i = 0; i < 8; ++i)
#pragma unroll
    for (int j = 0; j < 4; ++j) acc[i][j] = f32x4{0.f, 0.f, 0.f, 0.f};

  bf16x8 af[4][2];   // A fragments (mh0 then mh1; compiler may rename)
  bf16x8 bfr[4][2];  // all 4 n fragments (persistent across the tile)

  // ---- prologue: stage tile 0 (par0) fully + B of tile 1 (par1); tile 1's
  // A halves get staged during tile 0 region 1. vmcnt(4): tile-0 landed. ----
  STAGE_A(0, 0, 0)
  STAGE_A(0, 1, 0)
  STAGE_B(0, 0, 0)
  STAGE_B(0, 1, 0)
  STAGE_B(1, 0, 1)
  STAGE_B(1, 1, 1)
  WAIT_VM4();
  BARM()

  for (int t = 0; t < NT; t += 2) {
    KTILE(t, 0)
    KTILE(t + 1, 1)
  }
  WAIT_VM0();  // drain dangling clamped-tail prefetches before endpgm

  // ---- epilogue: C/D layout col=lane&15, row=(lane>>4)*4+r ----
  const int orow = (lane >> 4) * 4;
  const int ocol = lane & 15;
#pragma unroll
  for (int mi = 0; mi < 8; ++mi)
#pragma unroll
    for (int ni = 0; ni < 4; ++ni) {
      const long r0 = a_row0 + wr * 128 + mi * 16 + orow;
      const long c0 = b_row0 + wc * 64 + ni * 16 + ocol;
#pragma unroll
      for (int r = 0; r < 4; ++r) C[(r0 + r) * N + c0] = acc[mi][ni][r];
    }
}

// ---------------------------------------------------------------------------
// Launch
// ---------------------------------------------------------------------------
extern "C" void kernel_launch(void* const* d_in, const int* in_sizes, int n_in,
                              void* d_out, int out_size, void* d_ws,
                              size_t ws_size, hipStream_t stream) {
  const float* x = (const float*)d_in[0];
  const float* w = (const float*)d_in[1];
  float* out = (float*)d_out;

  const int K = 4096;
  const long M = (long)in_sizes[0] / K;  // 8192
  const int N = in_sizes[1] / K;         // 4096

  ushort_t* xsp = (ushort_t*)d_ws;      // [M][K] bf16
  ushort_t* wb = xsp + (long)M * K;     // [N][K] bf16

  const long n8x = M * K / 8;
  prune_cast_kernel<<<(int)((n8x + 255) / 256), 256, 0, stream>>>(x, xsp, n8x);

  const long n8w = (long)N * K / 8;
  cast_bf16_kernel<<<(int)((n8w + 255) / 256), 256, 0, stream>>>(w, wb, n8w);

  const int nwg = (int)(M / 256) * (N / 256);  // 512, divisible by 8
  gemm256_kernel<<<nwg, 512, 0, stream>>>(xsp, wb, out, (int)M, N, K);
}